// Round 6
// baseline (138.133 us; speedup 1.0000x reference)
//
#include <hip/hip_runtime.h>
#include <hip/hip_bf16.h>
#include <math.h>

// Problem: VOCAB=50257, E=64, D=16, DK=32, B*S=65536, membership p=0.05
#define EDIM 64
#define DDOM 16
#define DKDIM 32
#define NTHREADS 256
#define NBA 1024            // job-A blocks in prep (out = h streaming)
#define WPD 128             // waves per domain in mlp3 (32 blocks x 4 waves)

// ws layout: int cnt[16] @0 | float w1t[16][32][64] @256 | int lists[16][ntok]
//
// Domain-major, 3 dispatches: memset(cnt) -> prep -> mlp3.
// prep: jobA out=h stream; jobB membership detect + per-domain position
//       compaction; jobC W1 transpose into ws (w1t[d][k][e]).
// mlp3: NO weight LDS. Weight rows are wave-uniform -> compiler emits
//       s_load (scalar K$) for w1t/W2 rows; LDS pipe (R5 bottleneck:
//       1024 ds_read_b128/iter ~ 16us/CU) is freed. Lane = token, h and
//       c in VGPRs, fused step1+step2 per k, epilogue via per-wave padded
//       LDS transpose + coalesced row atomics. No __syncthreads in mlp3.

// ---------------------------------------------------------------------------
__global__ void prep_kernel(const int* __restrict__ x,
                            const float* __restrict__ tab,
                            const float* __restrict__ W1,   // [D][E][DK]
                            const unsigned char* __restrict__ memb,
                            float* __restrict__ out,
                            int* __restrict__ cnt,          // [16]
                            float* __restrict__ w1t,        // [16][32][64]
                            int* __restrict__ lists,        // [16][ntok]
                            int ntok, int nbb)
{
    const int thr = threadIdx.x;
    const int bid = blockIdx.x;
    if (bid < NBA) {
        // ---- job A: out = embed_table[x]  (coalesced float4 gather-stream)
        const int nf4 = ntok * 16;
        for (int i = bid * NTHREADS + thr; i < nf4; i += NBA * NTHREADS) {
            int t = i >> 4, s = i & 15;
            int tok = x[t];
            float4 hv = ((const float4*)(tab + (size_t)tok * EDIM))[s];
            ((float4*)(out + (size_t)t * EDIM))[s] = hv;
        }
        return;
    }
    if (bid >= NBA + nbb) {
        // ---- job C: transpose W1[d][e][k] -> w1t[d][k][e]  (one block/domain)
        const int d = bid - NBA - nbb;
        const float* __restrict__ src = W1 + d * (EDIM * DKDIM);
        float* __restrict__ dst = w1t + d * (EDIM * DKDIM);
        for (int i = thr; i < EDIM * DKDIM; i += NTHREADS) {
            int e = i >> 5, k = i & 31;          // src[e*32+k], coalesced read
            dst[k * EDIM + e] = src[i];
        }
        return;
    }
    // ---- job B: membership dtype detect + per-domain compaction
    __shared__ int det;
    __shared__ int lcnt[DDOM], lbase[DDOM], lpos[DDOM];
    if (thr == 0) det = 0;
    if (thr < DDOM) lcnt[thr] = 0;
    __syncthreads();
    {   // scan first 4096 bytes (membership >= 804112 elements >= 1 B: in-bounds)
        const uint4 v = ((const uint4*)memb)[thr];
        unsigned int w[4] = {v.x, v.y, v.z, v.w};
        int saw = 0;
        #pragma unroll
        for (int dw = 0; dw < 4; ++dw)
            #pragma unroll
            for (int b = 0; b < 4; ++b) {
                unsigned int byte = (w[dw] >> (8 * b)) & 0xFFu;
                if (byte > 1u) saw |= 1;            // bf16 signature bytes
                if (byte == 1u && b != 0) saw |= 2; // '1' at offset %4 != 0 -> u8
            }
        if (saw) atomicOr(&det, saw);
    }
    __syncthreads();
    const int mcode = det;

    const int t = (bid - NBA) * NTHREADS + thr;
    unsigned int m = 0;
    if (t < ntok) {
        int tok = x[t];
        if (mcode & 1) {          // bf16 0.0/1.0
            const unsigned short* p = (const unsigned short*)memb + (size_t)tok * DDOM;
            #pragma unroll
            for (int d = 0; d < DDOM; ++d) m |= (unsigned)(p[d] != 0) << d;
        } else if (mcode & 2) {   // uint8
            const unsigned char* p = memb + (size_t)tok * DDOM;
            #pragma unroll
            for (int d = 0; d < DDOM; ++d) m |= (unsigned)(p[d] != 0) << d;
        } else {                  // int32
            const int* p = (const int*)memb + (size_t)tok * DDOM;
            #pragma unroll
            for (int d = 0; d < DDOM; ++d) m |= (unsigned)(p[d] != 0) << d;
        }
    }
    #pragma unroll
    for (int d = 0; d < DDOM; ++d)
        if ((m >> d) & 1u) atomicAdd(&lcnt[d], 1);
    __syncthreads();
    if (thr < DDOM) {
        lbase[thr] = atomicAdd(&cnt[thr], lcnt[thr]);  // reserve global range
        lpos[thr] = 0;
    }
    __syncthreads();
    #pragma unroll
    for (int d = 0; d < DDOM; ++d)
        if ((m >> d) & 1u) {
            int p = atomicAdd(&lpos[d], 1);
            lists[(size_t)d * ntok + lbase[d] + p] = t;   // position
        }
}

// ---------------------------------------------------------------------------
// mlp3: grid = 16 domains x 32 blocks, 256 threads (4 waves), 2 blocks/CU.
// Lane = token; weight rows read via wave-uniform global loads (scalar path).
// ---------------------------------------------------------------------------
__global__ __launch_bounds__(256, 2) void mlp3_kernel(
    const int* __restrict__ lists,
    const int* __restrict__ cnt,
    const int* __restrict__ x,
    const float* __restrict__ tab,
    const float* __restrict__ w1t,  // [D][DK][E]  (transposed, in ws)
    const float* __restrict__ W2,   // [D][DK][E]
    float* __restrict__ out,
    int ntok)
{
    __shared__ float cbuf[4][64][17];    // per-wave transpose staging, 17.4 KB

    const int thr = threadIdx.x, lane = thr & 63, wid = thr >> 6;
    const int d   = blockIdx.x >> 5;     // 32 blocks/domain
    const int blk = blockIdx.x & 31;
    const int n   = cnt[d];

    const int wg = blk * 4 + wid;        // wave index within domain: 0..127
    for (int base = wg * 64; base < n; base += WPD * 64) {
        const int ti = base + lane;
        const bool valid = ti < n;
        const int pos   = valid ? lists[(size_t)d * ntok + ti] : 0;  // position
        const int tokid = valid ? x[pos] : 0;                        // token id

        float h[EDIM];
        {
            const float4* __restrict__ hr = (const float4*)(tab + (size_t)tokid * EDIM);
            #pragma unroll
            for (int i = 0; i < 16; ++i) ((float4*)h)[i] = hr[i];
        }

        float c[EDIM];
        #pragma unroll
        for (int e = 0; e < EDIM; ++e) c[e] = 0.f;

        // fused step1+step2 per k; all weight addresses wave-uniform -> s_load
        const float* __restrict__ w1d = w1t + d * (DKDIM * EDIM);
        const float* __restrict__ w2d = W2  + d * (DKDIM * EDIM);
        #pragma unroll 2
        for (int k = 0; k < DKDIM; ++k) {
            const float4* __restrict__ wr = (const float4*)(w1d + k * EDIM);
            float u0 = 0.f, u1 = 0.f, u2 = 0.f, u3 = 0.f;
            #pragma unroll
            for (int q = 0; q < 16; q += 4) {
                float4 a = wr[q + 0];
                u0 = fmaf(h[4*q+ 0], a.x, u0); u0 = fmaf(h[4*q+ 1], a.y, u0);
                u0 = fmaf(h[4*q+ 2], a.z, u0); u0 = fmaf(h[4*q+ 3], a.w, u0);
                float4 b = wr[q + 1];
                u1 = fmaf(h[4*q+ 4], b.x, u1); u1 = fmaf(h[4*q+ 5], b.y, u1);
                u1 = fmaf(h[4*q+ 6], b.z, u1); u1 = fmaf(h[4*q+ 7], b.w, u1);
                float4 e2 = wr[q + 2];
                u2 = fmaf(h[4*q+ 8], e2.x, u2); u2 = fmaf(h[4*q+ 9], e2.y, u2);
                u2 = fmaf(h[4*q+10], e2.z, u2); u2 = fmaf(h[4*q+11], e2.w, u2);
                float4 f2 = wr[q + 3];
                u3 = fmaf(h[4*q+12], f2.x, u3); u3 = fmaf(h[4*q+13], f2.y, u3);
                u3 = fmaf(h[4*q+14], f2.z, u3); u3 = fmaf(h[4*q+15], f2.w, u3);
            }
            float u = (u0 + u1) + (u2 + u3);
            // exact GELU u*Phi(u): odd Taylor (|u|~1.6e-3), guarded erff fallback
            float gg, au = fabsf(u);
            if (__builtin_expect(au > 0.35f, 0)) {
                gg = 0.5f * u * (1.f + erff(u * 0.70710678118654752f));
            } else {
                float uu = u * u;
                gg = u * (0.5f + u * (0.3989422804f + uu * (-0.06649038f + uu * 0.00997356f)));
            }
            const float4* __restrict__ w2r = (const float4*)(w2d + k * EDIM);
            #pragma unroll
            for (int q = 0; q < 16; ++q) {
                float4 w = w2r[q];
                c[4*q+0] = fmaf(gg, w.x, c[4*q+0]);
                c[4*q+1] = fmaf(gg, w.y, c[4*q+1]);
                c[4*q+2] = fmaf(gg, w.z, c[4*q+2]);
                c[4*q+3] = fmaf(gg, w.w, c[4*q+3]);
            }
        }

        // epilogue: per-wave LDS transpose (4 e-chunks of 16) + coalesced atomics
        const int r0 = lane >> 4;       // 4 token rows per atomic instr
        const int ee = lane & 15;       // e within chunk
        #pragma unroll
        for (int ec = 0; ec < 4; ++ec) {
            #pragma unroll
            for (int e = 0; e < 16; ++e)
                cbuf[wid][lane][e] = c[ec * 16 + e];   // same-wave RAW, in-order DS
            for (int rr = 0; rr < 64; rr += 4) {
                int tloc = rr + r0;
                int p2 = __shfl(pos, tloc, 64);        // all lanes active here
                if (base + tloc < n) {
                    atomicAdd(&out[(size_t)p2 * EDIM + ec * 16 + ee],
                              0.1f * cbuf[wid][tloc][ee]);
                }
            }
        }
    }
}

// ---------------------------------------------------------------------------
// Fallback (ws too small): round-2 fused kernel, known-correct.
// ---------------------------------------------------------------------------
__global__ __launch_bounds__(256, 4) void domain_embed_fused(
    const int* __restrict__ x, const float* __restrict__ tab,
    const float* __restrict__ W1, const float* __restrict__ W2,
    const unsigned char* __restrict__ memb, float* __restrict__ out, int ntok)
{
    __shared__ float h_lds[32][EDIM];
    __shared__ float corr[32][EDIM];
    __shared__ int   tok_lds[32];
    __shared__ unsigned int mask_lds[32];
    __shared__ unsigned short pairs[32 * DDOM];
    __shared__ int npairs;
    __shared__ int det_wave[4];
    const int thr = threadIdx.x, lane = thr & 63, wid = thr >> 6;
    const int tok0 = blockIdx.x * 32;
    if (thr < 32) { int t = tok0 + thr; tok_lds[thr] = (t < ntok) ? x[t] : 0; }
    #pragma unroll
    for (int i = 0; i < 8; ++i) ((float*)corr)[thr + i * 256] = 0.f;
    if (thr == 0) npairs = 0;
    {
        const uint4 v = ((const uint4*)memb)[thr];
        unsigned int w[4] = {v.x, v.y, v.z, v.w};
        bool sawbf = false, saw8 = false;
        #pragma unroll
        for (int dw = 0; dw < 4; ++dw)
            #pragma unroll
            for (int b = 0; b < 4; ++b) {
                unsigned int byte = (w[dw] >> (8 * b)) & 0xFFu;
                if (byte > 1u) sawbf = true;
                if (byte == 1u && b != 0) saw8 = true;
            }
        unsigned long long b1 = __ballot(sawbf), b2 = __ballot(saw8);
        if (lane == 0) det_wave[wid] = (b1 ? 1 : 0) | (b2 ? 2 : 0);
    }
    __syncthreads();
    const int mcode = det_wave[0] | det_wave[1] | det_wave[2] | det_wave[3];
    #pragma unroll
    for (int pass = 0; pass < 2; ++pass) {
        int row = pass * 16 + (thr >> 4);
        const float4 hv = ((const float4*)(tab + (size_t)tok_lds[row] * EDIM))[thr & 15];
        ((float4*)&h_lds[row][0])[thr & 15] = hv;
    }
    if (thr < 32) {
        int tokid = tok_lds[thr];
        unsigned int m = 0;
        if (mcode & 1) { const unsigned short* p = (const unsigned short*)memb + (size_t)tokid * DDOM;
            #pragma unroll
            for (int d = 0; d < DDOM; ++d) m |= (unsigned)(p[d] != 0) << d;
        } else if (mcode & 2) { const unsigned char* p = memb + (size_t)tokid * DDOM;
            #pragma unroll
            for (int d = 0; d < DDOM; ++d) m |= (unsigned)(p[d] != 0) << d;
        } else { const int* p = (const int*)memb + (size_t)tokid * DDOM;
            #pragma unroll
            for (int d = 0; d < DDOM; ++d) m |= (unsigned)(p[d] != 0) << d;
        }
        mask_lds[thr] = m;
    }
    __syncthreads();
    for (int cc = thr; cc < 32 * DDOM; cc += 256) {
        int t = cc >> 4, d = cc & 15;
        if ((mask_lds[t] >> d) & 1u) { int idx = atomicAdd(&npairs, 1); pairs[idx] = (unsigned short)cc; }
    }
    __syncthreads();
    const int np = npairs, k = lane & 31, p = lane >> 5;
    for (int pi = wid; pi < np; pi += 4) {
        int cc = pairs[pi], t = cc >> 4, d = cc & 15;
        const float* __restrict__ w1 = W1 + d * (EDIM * DKDIM);
        float u = 0.f;
        #pragma unroll
        for (int j4 = 0; j4 < 8; ++j4) {
            float4 hv = ((const float4*)&h_lds[t][p * 32])[j4];
            int e = p * 32 + j4 * 4;
            u = fmaf(hv.x, w1[(e + 0) * DKDIM + k], u);
            u = fmaf(hv.y, w1[(e + 1) * DKDIM + k], u);
            u = fmaf(hv.z, w1[(e + 2) * DKDIM + k], u);
            u = fmaf(hv.w, w1[(e + 3) * DKDIM + k], u);
        }
        u += __shfl_xor(u, 32, 64);
        float gg, au = fabsf(u);
        if (__builtin_expect(__ballot(au > 0.35f) != 0ull, 0))
            gg = 0.5f * u * (1.f + erff(u * 0.70710678118654752f));
        else { float uu = u * u; gg = u * (0.5f + u * (0.3989422804f + uu * (-0.06649038f + uu * 0.00997356f))); }
        const float* __restrict__ w2 = W2 + d * (DKDIM * EDIM);
        float cp = 0.f;
        #pragma unroll
        for (int kk = 0; kk < DKDIM; ++kk) cp = fmaf(__shfl(gg, kk, 64), w2[kk * EDIM + lane], cp);
        atomicAdd(&corr[t][lane], cp);
    }
    __syncthreads();
    #pragma unroll
    for (int pass = 0; pass < 2; ++pass) {
        int row = pass * 16 + (thr >> 4), gt = tok0 + row;
        if (gt < ntok) {
            float4 hv = ((const float4*)&h_lds[row][0])[thr & 15];
            float4 cv = ((const float4*)&corr[row][0])[thr & 15];
            float4 o = {hv.x + 0.1f * cv.x, hv.y + 0.1f * cv.y, hv.z + 0.1f * cv.z, hv.w + 0.1f * cv.w};
            ((float4*)(out + (size_t)gt * EDIM))[thr & 15] = o;
        }
    }
}

extern "C" void kernel_launch(void* const* d_in, const int* in_sizes, int n_in,
                              void* d_out, int out_size, void* d_ws, size_t ws_size,
                              hipStream_t stream) {
    const int*   x    = (const int*)  d_in[0];
    const float* tab  = (const float*)d_in[1];
    const float* W1   = (const float*)d_in[2];
    const float* W2   = (const float*)d_in[3];
    const unsigned char* memb = (const unsigned char*)d_in[4];
    float* out = (float*)d_out;
    const int ntok = in_sizes[0];

    // ws: cnt[16] @0 | w1t (128 KB) @256 | lists @256+131072
    const size_t w1t_off   = 256;
    const size_t lists_off = w1t_off + (size_t)DDOM * DKDIM * EDIM * sizeof(float);
    const size_t need      = lists_off + (size_t)DDOM * (size_t)ntok * sizeof(int);
    if (ws_size >= need) {
        int*   cnt   = (int*)d_ws;
        float* w1t   = (float*)((char*)d_ws + w1t_off);
        int*   lists = (int*)((char*)d_ws + lists_off);
        hipMemsetAsync(d_ws, 0, 64, stream);               // zero cnt (ws poisoned 0xAA)
        const int nbb = (ntok + NTHREADS - 1) / NTHREADS;
        prep_kernel<<<NBA + nbb + DDOM, NTHREADS, 0, stream>>>(
            x, tab, W1, memb, out, cnt, w1t, lists, ntok, nbb);
        mlp3_kernel<<<DDOM * 32, NTHREADS, 0, stream>>>(
            lists, cnt, x, tab, w1t, W2, out, ntok);
    } else {
        const int blocks = (ntok + 31) / 32;
        domain_embed_fused<<<blocks, NTHREADS, 0, stream>>>(x, tab, W1, W2, memb, out, ntok);
    }
}

// Round 7
// 124.252 us; speedup vs baseline: 1.1117x; 1.1117x over previous
//
#include <hip/hip_runtime.h>
#include <hip/hip_bf16.h>
#include <math.h>

// Problem: VOCAB=50257, E=64, D=16, DK=32, B*S=65536, membership p=0.05
#define EDIM 64
#define DDOM 16
#define DKDIM 32
#define NTHREADS 256
#define NBA 1024            // job-A blocks in prep (out = h streaming)
#define MBD 32              // blocks per domain in mlp4
#define CNT_STRIDE 32       // ints between cnt[d] atomic targets (128 B)

// ws layout: int cnt[16*CNT_STRIDE] @0 | int lists[16][ntok] @2048
//
// Domain-major. prep: jobA out=h stream; jobB membership detect + per-domain
// position compaction (cnt padded to 128 B/counter to avoid same-line atomic
// serialization). mlp4 = mlp2 structure (weights fp32 in LDS, lane=token,
// uniform-broadcast ds_read_b128, fused step1+step2, LDS-transpose epilogue)
// + K-SPLIT: two waves per token-group, each handling 16 of 32 k's, both
// atomicAdd into out. 2x concurrency (6.4 waves/CU), halved per-wave serial
// chain, same total DS instr count. h-gather issued before weight staging to
// hide its dependent-load chain under the stage+barrier.
// R6 lesson: global weight loads spill VGPRs (92 < h+c=128) -> LDS weights.

// ---------------------------------------------------------------------------
__global__ void prep_kernel(const int* __restrict__ x,
                            const float* __restrict__ tab,
                            const unsigned char* __restrict__ memb,
                            float* __restrict__ out,
                            int* __restrict__ cnt,      // [16*CNT_STRIDE]
                            int* __restrict__ lists,    // [16][ntok]
                            int ntok)
{
    const int thr = threadIdx.x;
    const int bid = blockIdx.x;
    if (bid < NBA) {
        // ---- job A: out = embed_table[x]  (coalesced float4 gather-stream)
        const int nf4 = ntok * 16;
        for (int i = bid * NTHREADS + thr; i < nf4; i += NBA * NTHREADS) {
            int t = i >> 4, s = i & 15;
            int tok = x[t];
            float4 hv = ((const float4*)(tab + (size_t)tok * EDIM))[s];
            ((float4*)(out + (size_t)t * EDIM))[s] = hv;
        }
        return;
    }
    // ---- job B: membership dtype detect + per-domain compaction
    __shared__ int det;
    __shared__ int lcnt[DDOM], lbase[DDOM], lpos[DDOM];
    if (thr == 0) det = 0;
    if (thr < DDOM) lcnt[thr] = 0;
    __syncthreads();
    {   // scan first 4096 bytes (membership >= 804112 elements >= 1 B: in-bounds)
        const uint4 v = ((const uint4*)memb)[thr];
        unsigned int w[4] = {v.x, v.y, v.z, v.w};
        int saw = 0;
        #pragma unroll
        for (int dw = 0; dw < 4; ++dw)
            #pragma unroll
            for (int b = 0; b < 4; ++b) {
                unsigned int byte = (w[dw] >> (8 * b)) & 0xFFu;
                if (byte > 1u) saw |= 1;            // bf16 signature bytes
                if (byte == 1u && b != 0) saw |= 2; // '1' at offset %4 != 0 -> u8
            }
        if (saw) atomicOr(&det, saw);
    }
    __syncthreads();
    const int mcode = det;

    const int t = (bid - NBA) * NTHREADS + thr;
    unsigned int m = 0;
    if (t < ntok) {
        int tok = x[t];
        if (mcode & 1) {          // bf16 0.0/1.0
            const unsigned short* p = (const unsigned short*)memb + (size_t)tok * DDOM;
            #pragma unroll
            for (int d = 0; d < DDOM; ++d) m |= (unsigned)(p[d] != 0) << d;
        } else if (mcode & 2) {   // uint8
            const unsigned char* p = memb + (size_t)tok * DDOM;
            #pragma unroll
            for (int d = 0; d < DDOM; ++d) m |= (unsigned)(p[d] != 0) << d;
        } else {                  // int32
            const int* p = (const int*)memb + (size_t)tok * DDOM;
            #pragma unroll
            for (int d = 0; d < DDOM; ++d) m |= (unsigned)(p[d] != 0) << d;
        }
    }
    #pragma unroll
    for (int d = 0; d < DDOM; ++d)
        if ((m >> d) & 1u) atomicAdd(&lcnt[d], 1);
    __syncthreads();
    if (thr < DDOM) {
        lbase[thr] = atomicAdd(&cnt[thr * CNT_STRIDE], lcnt[thr]);  // padded target
        lpos[thr] = 0;
    }
    __syncthreads();
    #pragma unroll
    for (int d = 0; d < DDOM; ++d)
        if ((m >> d) & 1u) {
            int p = atomicAdd(&lpos[d], 1);
            lists[(size_t)d * ntok + lbase[d] + p] = t;   // position
        }
}

// ---------------------------------------------------------------------------
// mlp4: grid = 16 domains x 32 blocks, 256 threads (4 waves), 2 blocks/CU.
// Wave = (token-group, k-half). Lane = token. Weights fp32 LDS broadcast.
// ---------------------------------------------------------------------------
__global__ __launch_bounds__(256, 2) void mlp4_kernel(
    const int* __restrict__ lists,
    const int* __restrict__ cnt,
    const int* __restrict__ x,
    const float* __restrict__ tab,
    const float* __restrict__ W1,   // [D][E][DK]
    const float* __restrict__ W2,   // [D][DK][E]
    float* __restrict__ out,
    int ntok)
{
    __shared__ float w1t[DKDIM][68];   // W1[d]^T: [k][e], pad 68 (16B-aligned rows)
    __shared__ float w2s[DKDIM][68];   // W2[d]:  [k][e]
    __shared__ float cbuf[4][64][17];  // per-wave transpose staging

    const int thr = threadIdx.x, lane = thr & 63, wid = thr >> 6;
    const int d   = blockIdx.x >> 5;
    const int blk = blockIdx.x & (MBD - 1);
    const int n   = cnt[d * CNT_STRIDE];
    if (blk * 2 * 64 >= n) return;       // block-uniform early-exit (pre-stage/sync)

    const int grp0  = blk * 2 + (wid >> 1);   // token-group for this wave
    const int khalf = wid & 1;                // k-half for this wave
    const int k0    = khalf * 16;

    // ---- issue first h-gather BEFORE staging (hide dependent chain) ----
    int base = grp0 * 64;
    int ti = base + lane;
    bool valid = (base < n) && (ti < n);
    int pos   = valid ? lists[(size_t)d * ntok + ti] : 0;
    int tokid = valid ? x[pos] : 0;
    float h[EDIM];
    {
        const float4* __restrict__ hr = (const float4*)(tab + (size_t)tokid * EDIM);
        #pragma unroll
        for (int i = 0; i < 16; ++i) ((float4*)h)[i] = hr[i];
    }

    // ---- stage this domain's weights once ----
    const float* __restrict__ w1g = W1 + d * (EDIM * DKDIM);
    for (int i = thr; i < EDIM * DKDIM; i += NTHREADS) {
        int e = i >> 5, k = i & 31;      // w1g is [e][k], coalesced read
        w1t[k][e] = w1g[i];
    }
    const float* __restrict__ w2g = W2 + d * (DKDIM * EDIM);
    for (int i = thr; i < DKDIM * EDIM; i += NTHREADS) {
        w2s[i >> 6][i & 63] = w2g[i];
    }
    __syncthreads();

    for (; base < n; ) {
        float c[EDIM];
        #pragma unroll
        for (int e = 0; e < EDIM; ++e) c[e] = 0.f;

        // fused step1+step2 over this wave's 16 k's
        #pragma unroll 2
        for (int kk = 0; kk < 16; ++kk) {
            const int k = k0 + kk;
            const float4* __restrict__ wr = (const float4*)&w1t[k][0];  // uniform
            float u0 = 0.f, u1 = 0.f, u2 = 0.f, u3 = 0.f;
            #pragma unroll
            for (int q = 0; q < 16; q += 4) {
                float4 a = wr[q + 0];
                u0 = fmaf(h[4*q+ 0], a.x, u0); u0 = fmaf(h[4*q+ 1], a.y, u0);
                u0 = fmaf(h[4*q+ 2], a.z, u0); u0 = fmaf(h[4*q+ 3], a.w, u0);
                float4 b = wr[q + 1];
                u1 = fmaf(h[4*q+ 4], b.x, u1); u1 = fmaf(h[4*q+ 5], b.y, u1);
                u1 = fmaf(h[4*q+ 6], b.z, u1); u1 = fmaf(h[4*q+ 7], b.w, u1);
                float4 e2 = wr[q + 2];
                u2 = fmaf(h[4*q+ 8], e2.x, u2); u2 = fmaf(h[4*q+ 9], e2.y, u2);
                u2 = fmaf(h[4*q+10], e2.z, u2); u2 = fmaf(h[4*q+11], e2.w, u2);
                float4 f2 = wr[q + 3];
                u3 = fmaf(h[4*q+12], f2.x, u3); u3 = fmaf(h[4*q+13], f2.y, u3);
                u3 = fmaf(h[4*q+14], f2.z, u3); u3 = fmaf(h[4*q+15], f2.w, u3);
            }
            float u = (u0 + u1) + (u2 + u3);
            // exact GELU u*Phi(u): odd Taylor (|u|~1.6e-3), guarded erff fallback
            float gg, au = fabsf(u);
            if (__builtin_expect(au > 0.35f, 0)) {
                gg = 0.5f * u * (1.f + erff(u * 0.70710678118654752f));
            } else {
                float uu = u * u;
                gg = u * (0.5f + u * (0.3989422804f + uu * (-0.06649038f + uu * 0.00997356f)));
            }
            const float4* __restrict__ w2r = (const float4*)&w2s[k][0];  // uniform
            #pragma unroll
            for (int q = 0; q < 16; ++q) {
                float4 w = w2r[q];
                c[4*q+0] = fmaf(gg, w.x, c[4*q+0]);
                c[4*q+1] = fmaf(gg, w.y, c[4*q+1]);
                c[4*q+2] = fmaf(gg, w.z, c[4*q+2]);
                c[4*q+3] = fmaf(gg, w.w, c[4*q+3]);
            }
        }

        // epilogue: per-wave LDS transpose (4 e-chunks of 16) + coalesced atomics
        const int savedbase = base;
        const int savedpos  = pos;
        const int r0 = lane >> 4;
        const int ee = lane & 15;
        #pragma unroll
        for (int ec = 0; ec < 4; ++ec) {
            #pragma unroll
            for (int e = 0; e < 16; ++e)
                cbuf[wid][lane][e] = c[ec * 16 + e];   // same-wave RAW, in-order DS
            for (int rr = 0; rr < 64; rr += 4) {
                int tloc = rr + r0;
                int p2 = __shfl(savedpos, tloc, 64);   // all lanes active
                if (savedbase + tloc < n) {
                    atomicAdd(&out[(size_t)p2 * EDIM + ec * 16 + ee],
                              0.1f * cbuf[wid][tloc][ee]);
                }
            }
        }

        // next token-group for this wave (stride = 64 groups across domain)
        base += MBD * 2 * 64;
        if (base < n) {
            ti = base + lane;
            valid = ti < n;
            pos   = valid ? lists[(size_t)d * ntok + ti] : 0;
            tokid = valid ? x[pos] : 0;
            const float4* __restrict__ hr = (const float4*)(tab + (size_t)tokid * EDIM);
            #pragma unroll
            for (int i = 0; i < 16; ++i) ((float4*)h)[i] = hr[i];
        }
    }
}

// ---------------------------------------------------------------------------
// Fallback (ws too small): round-2 fused kernel, known-correct.
// ---------------------------------------------------------------------------
__global__ __launch_bounds__(256, 4) void domain_embed_fused(
    const int* __restrict__ x, const float* __restrict__ tab,
    const float* __restrict__ W1, const float* __restrict__ W2,
    const unsigned char* __restrict__ memb, float* __restrict__ out, int ntok)
{
    __shared__ float h_lds[32][EDIM];
    __shared__ float corr[32][EDIM];
    __shared__ int   tok_lds[32];
    __shared__ unsigned int mask_lds[32];
    __shared__ unsigned short pairs[32 * DDOM];
    __shared__ int npairs;
    __shared__ int det_wave[4];
    const int thr = threadIdx.x, lane = thr & 63, wid = thr >> 6;
    const int tok0 = blockIdx.x * 32;
    if (thr < 32) { int t = tok0 + thr; tok_lds[thr] = (t < ntok) ? x[t] : 0; }
    #pragma unroll
    for (int i = 0; i < 8; ++i) ((float*)corr)[thr + i * 256] = 0.f;
    if (thr == 0) npairs = 0;
    {
        const uint4 v = ((const uint4*)memb)[thr];
        unsigned int w[4] = {v.x, v.y, v.z, v.w};
        bool sawbf = false, saw8 = false;
        #pragma unroll
        for (int dw = 0; dw < 4; ++dw)
            #pragma unroll
            for (int b = 0; b < 4; ++b) {
                unsigned int byte = (w[dw] >> (8 * b)) & 0xFFu;
                if (byte > 1u) sawbf = true;
                if (byte == 1u && b != 0) saw8 = true;
            }
        unsigned long long b1 = __ballot(sawbf), b2 = __ballot(saw8);
        if (lane == 0) det_wave[wid] = (b1 ? 1 : 0) | (b2 ? 2 : 0);
    }
    __syncthreads();
    const int mcode = det_wave[0] | det_wave[1] | det_wave[2] | det_wave[3];
    #pragma unroll
    for (int pass = 0; pass < 2; ++pass) {
        int row = pass * 16 + (thr >> 4);
        const float4 hv = ((const float4*)(tab + (size_t)tok_lds[row] * EDIM))[thr & 15];
        ((float4*)&h_lds[row][0])[thr & 15] = hv;
    }
    if (thr < 32) {
        int tokid = tok_lds[thr];
        unsigned int m = 0;
        if (mcode & 1) { const unsigned short* p = (const unsigned short*)memb + (size_t)tokid * DDOM;
            #pragma unroll
            for (int d = 0; d < DDOM; ++d) m |= (unsigned)(p[d] != 0) << d;
        } else if (mcode & 2) { const unsigned char* p = memb + (size_t)tokid * DDOM;
            #pragma unroll
            for (int d = 0; d < DDOM; ++d) m |= (unsigned)(p[d] != 0) << d;
        } else { const int* p = (const int*)memb + (size_t)tokid * DDOM;
            #pragma unroll
            for (int d = 0; d < DDOM; ++d) m |= (unsigned)(p[d] != 0) << d;
        }
        mask_lds[thr] = m;
    }
    __syncthreads();
    for (int cc = thr; cc < 32 * DDOM; cc += 256) {
        int t = cc >> 4, d = cc & 15;
        if ((mask_lds[t] >> d) & 1u) { int idx = atomicAdd(&npairs, 1); pairs[idx] = (unsigned short)cc; }
    }
    __syncthreads();
    const int np = npairs, k = lane & 31, p = lane >> 5;
    for (int pi = wid; pi < np; pi += 4) {
        int cc = pairs[pi], t = cc >> 4, d = cc & 15;
        const float* __restrict__ w1 = W1 + d * (EDIM * DKDIM);
        float u = 0.f;
        #pragma unroll
        for (int j4 = 0; j4 < 8; ++j4) {
            float4 hv = ((const float4*)&h_lds[t][p * 32])[j4];
            int e = p * 32 + j4 * 4;
            u = fmaf(hv.x, w1[(e + 0) * DKDIM + k], u);
            u = fmaf(hv.y, w1[(e + 1) * DKDIM + k], u);
            u = fmaf(hv.z, w1[(e + 2) * DKDIM + k], u);
            u = fmaf(hv.w, w1[(e + 3) * DKDIM + k], u);
        }
        u += __shfl_xor(u, 32, 64);
        float gg, au = fabsf(u);
        if (__builtin_expect(__ballot(au > 0.35f) != 0ull, 0))
            gg = 0.5f * u * (1.f + erff(u * 0.70710678118654752f));
        else { float uu = u * u; gg = u * (0.5f + u * (0.3989422804f + uu * (-0.06649038f + uu * 0.00997356f))); }
        const float* __restrict__ w2 = W2 + d * (DKDIM * EDIM);
        float cp = 0.f;
        #pragma unroll
        for (int kk = 0; kk < DKDIM; ++kk) cp = fmaf(__shfl(gg, kk, 64), w2[kk * EDIM + lane], cp);
        atomicAdd(&corr[t][lane], cp);
    }
    __syncthreads();
    #pragma unroll
    for (int pass = 0; pass < 2; ++pass) {
        int row = pass * 16 + (thr >> 4), gt = tok0 + row;
        if (gt < ntok) {
            float4 hv = ((const float4*)&h_lds[row][0])[thr & 15];
            float4 cv = ((const float4*)&corr[row][0])[thr & 15];
            float4 o = {hv.x + 0.1f * cv.x, hv.y + 0.1f * cv.y, hv.z + 0.1f * cv.z, hv.w + 0.1f * cv.w};
            ((float4*)(out + (size_t)gt * EDIM))[thr & 15] = o;
        }
    }
}

extern "C" void kernel_launch(void* const* d_in, const int* in_sizes, int n_in,
                              void* d_out, int out_size, void* d_ws, size_t ws_size,
                              hipStream_t stream) {
    const int*   x    = (const int*)  d_in[0];
    const float* tab  = (const float*)d_in[1];
    const float* W1   = (const float*)d_in[2];
    const float* W2   = (const float*)d_in[3];
    const unsigned char* memb = (const unsigned char*)d_in[4];
    float* out = (float*)d_out;
    const int ntok = in_sizes[0];

    // ws: cnt[16*CNT_STRIDE] @0 (2048 B) | lists @2048
    const size_t lists_off = (size_t)DDOM * CNT_STRIDE * sizeof(int);
    const size_t need      = lists_off + (size_t)DDOM * (size_t)ntok * sizeof(int);
    if (ws_size >= need) {
        int* cnt   = (int*)d_ws;
        int* lists = (int*)((char*)d_ws + lists_off);
        hipMemsetAsync(d_ws, 0, lists_off, stream);        // zero cnt (ws poisoned 0xAA)
        const int nbb = (ntok + NTHREADS - 1) / NTHREADS;
        prep_kernel<<<NBA + nbb, NTHREADS, 0, stream>>>(
            x, tab, memb, out, cnt, lists, ntok);
        mlp4_kernel<<<DDOM * MBD, NTHREADS, 0, stream>>>(
            lists, cnt, x, tab, W1, W2, out, ntok);
    } else {
        const int blocks = (ntok + 31) / 32;
        domain_embed_fused<<<blocks, NTHREADS, 0, stream>>>(x, tab, W1, W2, memb, out, ntok);
    }
}

// Round 8
// 100.476 us; speedup vs baseline: 1.3748x; 1.2366x over previous
//
#include <hip/hip_runtime.h>
#include <hip/hip_bf16.h>
#include <math.h>

// Problem: VOCAB=50257, E=64, D=16, DK=32, B*S=65536, membership p=0.05
#define EDIM 64
#define DDOM 16
#define DKDIM 32
#define NTHREADS 256
#define NBA 1024            // job-A blocks in prep (out = h streaming)
#define MBD 32              // blocks per domain in mlp5
#define CNT_STRIDE 32       // ints between cnt[d] atomic targets (128 B)

// ws layout: int cnt[16*CNT_STRIDE] @0 | int lists[16][ntok] @2048
//
// Domain-major + MFMA. prep: jobA out=h stream; jobB membership detect +
// per-domain position compaction. mlp5: one domain per block-group; W1/W2
// held in MFMA B-FRAGMENTS (bf16, 32 VGPRs) loaded ONCE per wave -> zero
// per-iteration weight reads (R2..R7 plateau was 16 LDS broadcasts/token,
// structurally unavoidable while lane=token). Per 16-token group:
//   step1 U[16x32] = H[16x64] x W1 (2 n-half frags x 2 K-tiles = 4 mfma)
//   gelu on D-frags, repack D->A layout via padded LDS (m120 pattern)
//   step2 C[16x64] = U[16x32] x W2 (4 mfma), atomicAdd 0.1*corr into out.
// Layouts (16x16x32 bf16, HW-verified refs): A[m=lane&15][k=quad*8+j];
// C/D col=lane&15,row=quad*4+reg; B[k=quad*8+j][n=lane&15].

typedef __attribute__((ext_vector_type(8))) short bf16x8;
typedef __attribute__((ext_vector_type(4))) float f32x4;

__device__ __forceinline__ short f2bf(float f) {   // fp32 -> bf16 bits, RNE
    unsigned u = __float_as_uint(f);
    u += 0x7FFFu + ((u >> 16) & 1u);
    return (short)(u >> 16);
}

// ---------------------------------------------------------------------------
__global__ void prep_kernel(const int* __restrict__ x,
                            const float* __restrict__ tab,
                            const unsigned char* __restrict__ memb,
                            float* __restrict__ out,
                            int* __restrict__ cnt,      // [16*CNT_STRIDE]
                            int* __restrict__ lists,    // [16][ntok]
                            int ntok)
{
    const int thr = threadIdx.x;
    const int bid = blockIdx.x;
    if (bid < NBA) {
        // ---- job A: out = embed_table[x]  (coalesced float4 gather-stream)
        const int nf4 = ntok * 16;
        for (int i = bid * NTHREADS + thr; i < nf4; i += NBA * NTHREADS) {
            int t = i >> 4, s = i & 15;
            int tok = x[t];
            float4 hv = ((const float4*)(tab + (size_t)tok * EDIM))[s];
            ((float4*)(out + (size_t)t * EDIM))[s] = hv;
        }
        return;
    }
    // ---- job B: membership dtype detect + per-domain compaction
    __shared__ int det;
    __shared__ int lcnt[DDOM], lbase[DDOM], lpos[DDOM];
    if (thr == 0) det = 0;
    if (thr < DDOM) lcnt[thr] = 0;
    __syncthreads();
    {   // scan first 4096 bytes (membership >= 804112 elements >= 1 B: in-bounds)
        const uint4 v = ((const uint4*)memb)[thr];
        unsigned int w[4] = {v.x, v.y, v.z, v.w};
        int saw = 0;
        #pragma unroll
        for (int dw = 0; dw < 4; ++dw)
            #pragma unroll
            for (int b = 0; b < 4; ++b) {
                unsigned int byte = (w[dw] >> (8 * b)) & 0xFFu;
                if (byte > 1u) saw |= 1;            // bf16 signature bytes
                if (byte == 1u && b != 0) saw |= 2; // '1' at offset %4 != 0 -> u8
            }
        if (saw) atomicOr(&det, saw);
    }
    __syncthreads();
    const int mcode = det;

    const int t = (bid - NBA) * NTHREADS + thr;
    unsigned int m = 0;
    if (t < ntok) {
        int tok = x[t];
        if (mcode & 1) {          // bf16 0.0/1.0
            const unsigned short* p = (const unsigned short*)memb + (size_t)tok * DDOM;
            #pragma unroll
            for (int d = 0; d < DDOM; ++d) m |= (unsigned)(p[d] != 0) << d;
        } else if (mcode & 2) {   // uint8
            const unsigned char* p = memb + (size_t)tok * DDOM;
            #pragma unroll
            for (int d = 0; d < DDOM; ++d) m |= (unsigned)(p[d] != 0) << d;
        } else {                  // int32
            const int* p = (const int*)memb + (size_t)tok * DDOM;
            #pragma unroll
            for (int d = 0; d < DDOM; ++d) m |= (unsigned)(p[d] != 0) << d;
        }
    }
    #pragma unroll
    for (int d = 0; d < DDOM; ++d)
        if ((m >> d) & 1u) atomicAdd(&lcnt[d], 1);
    __syncthreads();
    if (thr < DDOM) {
        lbase[thr] = atomicAdd(&cnt[thr * CNT_STRIDE], lcnt[thr]);  // padded target
        lpos[thr] = 0;
    }
    __syncthreads();
    #pragma unroll
    for (int d = 0; d < DDOM; ++d)
        if ((m >> d) & 1u) {
            int p = atomicAdd(&lpos[d], 1);
            lists[(size_t)d * ntok + lbase[d] + p] = t;   // position
        }
}

// ---------------------------------------------------------------------------
// mlp5: grid = 16 domains x 32 blocks, 256 threads (4 waves), 2 blocks/CU.
// Wave processes 16-token groups; weights live in bf16 MFMA fragments.
// ---------------------------------------------------------------------------
__global__ __launch_bounds__(256, 2) void mlp5_kernel(
    const int* __restrict__ lists,
    const int* __restrict__ cnt,
    const int* __restrict__ x,
    const float* __restrict__ tab,
    const float* __restrict__ W1,   // [D][E][DK]
    const float* __restrict__ W2,   // [D][DK][E]
    float* __restrict__ out,
    int ntok)
{
    __shared__ float u_lds[4][16][36];   // per-wave U repack, 36-stride (pad) 9.2 KB

    const int thr = threadIdx.x, lane = thr & 63, wid = thr >> 6;
    const int d    = blockIdx.x >> 5;
    const int blk  = blockIdx.x & (MBD - 1);
    const int n    = cnt[d * CNT_STRIDE];
    if (n == 0) return;

    const int col  = lane & 15;   // n-index inside a 16-wide tile
    const int quad = lane >> 4;   // k-index base = quad*8

    // ---- weight fragments, once per wave. B[k=quad*8+j][n=col] ----
    const float* __restrict__ w1g = W1 + d * (EDIM * DKDIM);  // [e][ko]
    const float* __restrict__ w2g = W2 + d * (DKDIM * EDIM);  // [k][e]
    bf16x8 w1f[2][2];   // [K-tile tk: e=tk*32+quad*8+j][n-half tn: ko=tn*16+col]
    #pragma unroll
    for (int tk = 0; tk < 2; ++tk)
        #pragma unroll
        for (int tn = 0; tn < 2; ++tn)
            #pragma unroll
            for (int j = 0; j < 8; ++j)
                w1f[tk][tn][j] = f2bf(w1g[(tk * 32 + quad * 8 + j) * DKDIM + tn * 16 + col]);
    bf16x8 w2f[4];      // [e-tile te: k=quad*8+j, n=e=te*16+col]
    #pragma unroll
    for (int te = 0; te < 4; ++te)
        #pragma unroll
        for (int j = 0; j < 8; ++j)
            w2f[te][j] = f2bf(w2g[(quad * 8 + j) * EDIM + te * 16 + col]);

    const int ngrp = (n + 15) >> 4;
    for (int g = blk * 4 + wid; g < ngrp; g += MBD * 4) {
        const int base = g * 16;
        // lane carries token row m=col of this group
        const int ti = base + col;
        const bool v = ti < n;
        const int pos   = v ? lists[(size_t)d * ntok + ti] : 0;
        const int tokid = v ? x[pos] : 0;

        // A-fragments of h: A[m=col][k=e=tk*32+quad*8+j]
        const float* __restrict__ hrow = tab + (size_t)tokid * EDIM;
        bf16x8 ha[2];
        #pragma unroll
        for (int tk = 0; tk < 2; ++tk) {
            f32x4 a = *(const f32x4*)(hrow + tk * 32 + quad * 8);
            f32x4 b = *(const f32x4*)(hrow + tk * 32 + quad * 8 + 4);
            ha[tk][0] = f2bf(a.x); ha[tk][1] = f2bf(a.y);
            ha[tk][2] = f2bf(a.z); ha[tk][3] = f2bf(a.w);
            ha[tk][4] = f2bf(b.x); ha[tk][5] = f2bf(b.y);
            ha[tk][6] = f2bf(b.z); ha[tk][7] = f2bf(b.w);
        }

        // ---- step1: U[16 tok x 32 ko], 2 n-halves x K=64 (2 mfma each) ----
        #pragma unroll
        for (int tn = 0; tn < 2; ++tn) {
            f32x4 acc = {0.f, 0.f, 0.f, 0.f};
            acc = __builtin_amdgcn_mfma_f32_16x16x32_bf16(ha[0], w1f[0][tn], acc, 0, 0, 0);
            acc = __builtin_amdgcn_mfma_f32_16x16x32_bf16(ha[1], w1f[1][tn], acc, 0, 0, 0);
            // gelu on D-frag (D[m=quad*4+r][ko=tn*16+col]) -> u_lds[m][ko]
            #pragma unroll
            for (int r = 0; r < 4; ++r) {
                float u = acc[r];
                float gg, au = fabsf(u);
                if (__builtin_expect(au > 0.35f, 0)) {
                    gg = 0.5f * u * (1.f + erff(u * 0.70710678118654752f));
                } else {
                    float uu = u * u;
                    gg = u * (0.5f + u * (0.3989422804f + uu * (-0.06649038f + uu * 0.00997356f)));
                }
                u_lds[wid][quad * 4 + r][tn * 16 + col] = gg;
            }
        }

        // ---- repack U: D-layout -> A-layout (same-wave RAW via in-order DS) ----
        bf16x8 ua;
        {
            const float* __restrict__ up = &u_lds[wid][col][quad * 8];
            f32x4 a = *(const f32x4*)(up);
            f32x4 b = *(const f32x4*)(up + 4);
            ua[0] = f2bf(a.x); ua[1] = f2bf(a.y); ua[2] = f2bf(a.z); ua[3] = f2bf(a.w);
            ua[4] = f2bf(b.x); ua[5] = f2bf(b.y); ua[6] = f2bf(b.z); ua[7] = f2bf(b.w);
        }

        // ---- step2: C[16 tok x 64 e] = U x W2; atomicAdd 0.1*corr ----
        #pragma unroll
        for (int te = 0; te < 4; ++te) {
            f32x4 acc = {0.f, 0.f, 0.f, 0.f};
            acc = __builtin_amdgcn_mfma_f32_16x16x32_bf16(ua, w2f[te], acc, 0, 0, 0);
            #pragma unroll
            for (int r = 0; r < 4; ++r) {
                int m  = quad * 4 + r;
                int pm = __shfl(pos, m, 64);      // pos of token row m
                if (base + m < n) {
                    atomicAdd(&out[(size_t)pm * EDIM + te * 16 + col], 0.1f * acc[r]);
                }
            }
        }
    }
}

// ---------------------------------------------------------------------------
// Fallback (ws too small): round-2 fused kernel, known-correct.
// ---------------------------------------------------------------------------
__global__ __launch_bounds__(256, 4) void domain_embed_fused(
    const int* __restrict__ x, const float* __restrict__ tab,
    const float* __restrict__ W1, const float* __restrict__ W2,
    const unsigned char* __restrict__ memb, float* __restrict__ out, int ntok)
{
    __shared__ float h_lds[32][EDIM];
    __shared__ float corr[32][EDIM];
    __shared__ int   tok_lds[32];
    __shared__ unsigned int mask_lds[32];
    __shared__ unsigned short pairs[32 * DDOM];
    __shared__ int npairs;
    __shared__ int det_wave[4];
    const int thr = threadIdx.x, lane = thr & 63, wid = thr >> 6;
    const int tok0 = blockIdx.x * 32;
    if (thr < 32) { int t = tok0 + thr; tok_lds[thr] = (t < ntok) ? x[t] : 0; }
    #pragma unroll
    for (int i = 0; i < 8; ++i) ((float*)corr)[thr + i * 256] = 0.f;
    if (thr == 0) npairs = 0;
    {
        const uint4 v = ((const uint4*)memb)[thr];
        unsigned int w[4] = {v.x, v.y, v.z, v.w};
        bool sawbf = false, saw8 = false;
        #pragma unroll
        for (int dw = 0; dw < 4; ++dw)
            #pragma unroll
            for (int b = 0; b < 4; ++b) {
                unsigned int byte = (w[dw] >> (8 * b)) & 0xFFu;
                if (byte > 1u) sawbf = true;
                if (byte == 1u && b != 0) saw8 = true;
            }
        unsigned long long b1 = __ballot(sawbf), b2 = __ballot(saw8);
        if (lane == 0) det_wave[wid] = (b1 ? 1 : 0) | (b2 ? 2 : 0);
    }
    __syncthreads();
    const int mcode = det_wave[0] | det_wave[1] | det_wave[2] | det_wave[3];
    #pragma unroll
    for (int pass = 0; pass < 2; ++pass) {
        int row = pass * 16 + (thr >> 4);
        const float4 hv = ((const float4*)(tab + (size_t)tok_lds[row] * EDIM))[thr & 15];
        ((float4*)&h_lds[row][0])[thr & 15] = hv;
    }
    if (thr < 32) {
        int tokid = tok_lds[thr];
        unsigned int m = 0;
        if (mcode & 1) { const unsigned short* p = (const unsigned short*)memb + (size_t)tokid * DDOM;
            #pragma unroll
            for (int d = 0; d < DDOM; ++d) m |= (unsigned)(p[d] != 0) << d;
        } else if (mcode & 2) { const unsigned char* p = memb + (size_t)tokid * DDOM;
            #pragma unroll
            for (int d = 0; d < DDOM; ++d) m |= (unsigned)(p[d] != 0) << d;
        } else { const int* p = (const int*)memb + (size_t)tokid * DDOM;
            #pragma unroll
            for (int d = 0; d < DDOM; ++d) m |= (unsigned)(p[d] != 0) << d;
        }
        mask_lds[thr] = m;
    }
    __syncthreads();
    for (int cc = thr; cc < 32 * DDOM; cc += 256) {
        int t = cc >> 4, d = cc & 15;
        if ((mask_lds[t] >> d) & 1u) { int idx = atomicAdd(&npairs, 1); pairs[idx] = (unsigned short)cc; }
    }
    __syncthreads();
    const int np = npairs, k = lane & 31, p = lane >> 5;
    for (int pi = wid; pi < np; pi += 4) {
        int cc = pairs[pi], t = cc >> 4, d = cc & 15;
        const float* __restrict__ w1 = W1 + d * (EDIM * DKDIM);
        float u = 0.f;
        #pragma unroll
        for (int j4 = 0; j4 < 8; ++j4) {
            float4 hv = ((const float4*)&h_lds[t][p * 32])[j4];
            int e = p * 32 + j4 * 4;
            u = fmaf(hv.x, w1[(e + 0) * DKDIM + k], u);
            u = fmaf(hv.y, w1[(e + 1) * DKDIM + k], u);
            u = fmaf(hv.z, w1[(e + 2) * DKDIM + k], u);
            u = fmaf(hv.w, w1[(e + 3) * DKDIM + k], u);
        }
        u += __shfl_xor(u, 32, 64);
        float gg, au = fabsf(u);
        if (__builtin_expect(__ballot(au > 0.35f) != 0ull, 0))
            gg = 0.5f * u * (1.f + erff(u * 0.70710678118654752f));
        else { float uu = u * u; gg = u * (0.5f + u * (0.3989422804f + uu * (-0.06649038f + uu * 0.00997356f))); }
        const float* __restrict__ w2 = W2 + d * (DKDIM * EDIM);
        float cp = 0.f;
        #pragma unroll
        for (int kk = 0; kk < DKDIM; ++kk) cp = fmaf(__shfl(gg, kk, 64), w2[kk * EDIM + lane], cp);
        atomicAdd(&corr[t][lane], cp);
    }
    __syncthreads();
    #pragma unroll
    for (int pass = 0; pass < 2; ++pass) {
        int row = pass * 16 + (thr >> 4), gt = tok0 + row;
        if (gt < ntok) {
            float4 hv = ((const float4*)&h_lds[row][0])[thr & 15];
            float4 cv = ((const float4*)&corr[row][0])[thr & 15];
            float4 o = {hv.x + 0.1f * cv.x, hv.y + 0.1f * cv.y, hv.z + 0.1f * cv.z, hv.w + 0.1f * cv.w};
            ((float4*)(out + (size_t)gt * EDIM))[thr & 15] = o;
        }
    }
}

extern "C" void kernel_launch(void* const* d_in, const int* in_sizes, int n_in,
                              void* d_out, int out_size, void* d_ws, size_t ws_size,
                              hipStream_t stream) {
    const int*   x    = (const int*)  d_in[0];
    const float* tab  = (const float*)d_in[1];
    const float* W1   = (const float*)d_in[2];
    const float* W2   = (const float*)d_in[3];
    const unsigned char* memb = (const unsigned char*)d_in[4];
    float* out = (float*)d_out;
    const int ntok = in_sizes[0];

    // ws: cnt[16*CNT_STRIDE] @0 (2048 B) | lists @2048
    const size_t lists_off = (size_t)DDOM * CNT_STRIDE * sizeof(int);
    const size_t need      = lists_off + (size_t)DDOM * (size_t)ntok * sizeof(int);
    if (ws_size >= need) {
        int* cnt   = (int*)d_ws;
        int* lists = (int*)((char*)d_ws + lists_off);
        hipMemsetAsync(d_ws, 0, lists_off, stream);        // zero cnt (ws poisoned 0xAA)
        const int nbb = (ntok + NTHREADS - 1) / NTHREADS;
        prep_kernel<<<NBA + nbb, NTHREADS, 0, stream>>>(
            x, tab, memb, out, cnt, lists, ntok);
        mlp5_kernel<<<DDOM * MBD, NTHREADS, 0, stream>>>(
            lists, cnt, x, tab, W1, W2, out, ntok);
    } else {
        const int blocks = (ntok + 31) / 32;
        domain_embed_fused<<<blocks, NTHREADS, 0, stream>>>(x, tab, W1, W2, memb, out, ntok);
    }
}